// Round 4
// baseline (330.089 us; speedup 1.0000x reference)
//
#include <hip/hip_runtime.h>
#include <math.h>

// Problem constants (fixed by the reference harness)
#define BATCH 4
#define SEQ   4096
#define DIM   1024
#define TOPK  64          // min(GLOBAL_BUDGET=64, int(4096*0.05)=204)
#define RSTRIDE 10        // max(1, 4096 // 409)
#define RBUDGET 409       // min(4096, int(4096*0.1))
#define LOCALW  128

#define TOTAL_ROWS   (BATCH * SEQ)      // 16384
#define TOTAL_GROUPS (TOTAL_ROWS / 4)   // 4096 groups of 4 rows

// d_ws layout: scores (B*S floats) then flags (B*S bytes)
#define WS_SCORES_OFF 0
#define WS_FLAGS_OFF  (BATCH * SEQ * sizeof(float))

// Block roles in kernel X (latency-critical blocks FIRST):
#define X_TOPK_BLOCKS 4
#define X_SEL_BLOCKS  16
#define X_STATIC_BASE (X_TOPK_BLOCKS + X_SEL_BLOCKS)   // 20

struct TkS {                       // top-k radix select scratch (~23 KB)
    unsigned int su[SEQ];
    unsigned char gsel[SEQ];
    unsigned int hist[257];
    unsigned int sufA[257];
    unsigned int sufB[257];
    unsigned int bcast[2];
};
struct CntS {                      // connection-count scratch (~9.2 KB)
    unsigned int vb[256], hb[256];
    int tA[256], tB[256], tC[256], tD[256];
    int exV[256], exH[256];
    int red[256];
};
union SMemU { TkS tk; CntS cnt; };

// ---------------------------------------------------------------------------
// One wave (64 lanes) per (b,s) row: score = dot(hidden[b,s,:], W)
__global__ void scores_kernel(const float* __restrict__ hs,
                              const int* __restrict__ amask,
                              const float* __restrict__ W,
                              float* __restrict__ scores) {
    int row  = blockIdx.x * 4 + (threadIdx.x >> 6);   // 4 waves / block
    int lane = threadIdx.x & 63;
    const float4* h4 = (const float4*)(hs + (size_t)row * DIM);
    const float4* w4 = (const float4*)W;
    float acc = 0.0f;
#pragma unroll
    for (int k = 0; k < DIM / 4 / 64; ++k) {          // 4 iterations
        float4 h = h4[lane + 64 * k];
        float4 w = w4[lane + 64 * k];
        acc += h.x * w.x + h.y * w.y + h.z * w.z + h.w * w.w;
    }
#pragma unroll
    for (int off = 32; off; off >>= 1) acc += __shfl_down(acc, off, 64);
    if (lane == 0)
        scores[row] = amask[row] ? acc : -INFINITY;
}

// ---------------------------------------------------------------------------
// Analytic connection count from bit-packed column prefix sums (per batch).
// Runs in the same block that just wrote flags[b*SEQ..] (visible after barrier).
__device__ void counts_body(const unsigned char* __restrict__ flags,
                            float* __restrict__ out_eff,
                            int b, int t, CntS& s) {
    int base = b * SEQ;
    const unsigned char* fp = flags + base + t * 16;
    unsigned int myv = 0, myh = 0;
#pragma unroll
    for (int e = 0; e < 16; ++e) {
        unsigned char f = fp[e];
        unsigned int v = f & 1u;
        unsigned int h = v & ((f & 6u) ? 1u : 0u);
        myv |= v << e;
        myh |= h << e;
    }
    s.vb[t] = myv; s.hb[t] = myh;
    int sv = __popc(myv), sh = __popc(myh);
    s.tA[t] = sv; s.tC[t] = sh;
    __syncthreads();
    int* vsrc = s.tA; int* vdst = s.tB;
    int* hsrc = s.tC; int* hdst = s.tD;
    for (int d = 1; d < 256; d <<= 1) {
        int av = vsrc[t] + ((t >= d) ? vsrc[t - d] : 0);
        int ah = hsrc[t] + ((t >= d) ? hsrc[t - d] : 0);
        vdst[t] = av; hdst[t] = ah;
        __syncthreads();
        int* tmp = vsrc; vsrc = vdst; vdst = tmp;
        tmp = hsrc; hsrc = hdst; hdst = tmp;
    }
    s.exV[t] = vsrc[t] - sv;
    s.exH[t] = hsrc[t] - sh;
    __syncthreads();

    int exVt = s.exV[t];
    int exV8 = (t >= 8) ? s.exV[t - 8] : 0;
    int exH8 = (t >= 8) ? s.exH[t - 8] : 0;
    unsigned int vb8 = (t >= 8) ? s.vb[t - 8] : 0u;
    unsigned int hb8 = (t >= 8) ? s.hb[t - 8] : 0u;
    int cnt = 0;
#pragma unroll
    for (int e = 0; e < 16; ++e) {
        unsigned int m = (2u << e) - 1u;         // bits 0..e
        int validI = (int)((myv >> e) & 1u);
        int hotI   = (int)((myh >> e) & 1u);
        int cumVi = exVt + __popc(myv & m);      // cumV[i], i = t*16+e
        int c;
        if (t >= 8) {                            // i >= 128
            int cumVm = exV8 + __popc(vb8 & m);  // cumV[i-128]
            int cumHm = exH8 + __popc(hb8 & m);  // cumH[i-128]
            c = hotI ? cumVi : (cumVi - cumVm + cumHm);
        } else {
            c = cumVi;                           // i<128: window covers all
        }
        cnt += validI ? c : 0;
    }
    s.red[t] = cnt;
    __syncthreads();
    for (int s2 = 128; s2; s2 >>= 1) {
        if (t < s2) s.red[t] += s.red[t + s2];
        __syncthreads();
    }
    if (t == 0)
        out_eff[b] = (float)s.red[0] * (1.0f / ((float)SEQ * (float)SEQ));
}

// ---------------------------------------------------------------------------
// Fused kernel X:
//   blocks [0,4)      : exact top-64 per batch (radix select) -> flags, then
//                       connection counts (flags just written by this block)
//   blocks [4,20)     : out_selected = 1.0 everywhere (selected is all-True)
//   blocks [20,4116)  : flag-INDEPENDENT mask region: for each row i, columns
//                       j in [cut2(i), SEQ), cut2 = roundup16(i-127).
//                       There value = (j<=i) & vI & vJ (local band or zero).
// A/B this round: PLAIN (temporal) stores, not nontemporal — matching the
// harness fill kernel that demonstrates 6.5 TB/s on this same buffer.
__global__ void __launch_bounds__(256) fused_static_kernel(
        const float* __restrict__ scores,
        const int* __restrict__ amask,
        unsigned char* __restrict__ flags,
        float* __restrict__ out_sparse,
        float* __restrict__ out_selected,
        float* __restrict__ out_eff) {
    __shared__ SMemU sm;

    int bid = blockIdx.x;
    int t = threadIdx.x;

    if (bid < X_TOPK_BLOCKS) {
        // ---------------- top-k + flag emission (verified radix select) ----
        int b = bid;
        TkS& s = sm.tk;

        for (int k = t; k < SEQ; k += 256) {
            float sc = scores[b * SEQ + k];
            unsigned int x = __float_as_uint(sc);
            s.su[k] = (x & 0x80000000u) ? ~x : (x | 0x80000000u);
            s.gsel[k] = 0;
        }
        __syncthreads();

        unsigned int prefixVal = 0;
        unsigned int remaining = TOPK;
#pragma unroll
        for (int pass = 0; pass < 4; ++pass) {
            int shift = 24 - 8 * pass;
            unsigned int highmask = (pass == 0) ? 0u : (0xFFFFFFFFu << (shift + 8));

            s.hist[t] = 0;
            if (t == 0) s.hist[256] = 0;
            __syncthreads();

#pragma unroll
            for (int e = 0; e < SEQ / 256; ++e) {
                unsigned int u = s.su[t * (SEQ / 256) + e];
                if ((u & highmask) == prefixVal)
                    atomicAdd(&s.hist[(u >> shift) & 0xFFu], 1u);
            }
            __syncthreads();

            s.sufA[t] = s.hist[t];
            if (t == 0) s.sufA[256] = 0;
            __syncthreads();
            unsigned int* src = s.sufA;
            unsigned int* dst = s.sufB;
            for (int d = 1; d < 256; d <<= 1) {
                unsigned int v = src[t] + ((t + d < 256) ? src[t + d] : 0u);
                dst[t] = v;
                if (t == 0) dst[256] = 0;
                __syncthreads();
                unsigned int* tmp = src; src = dst; dst = tmp;
            }
            if (src[t] >= remaining && src[t + 1] < remaining) {
                s.bcast[0] = (unsigned int)t;
                s.bcast[1] = remaining - src[t + 1];
            }
            __syncthreads();
            prefixVal |= (s.bcast[0] << shift);
            remaining = s.bcast[1];
            __syncthreads();
        }

        // stable selection of `remaining` lowest-index elements equal to T
        unsigned int T = prefixVal;
        unsigned int myeq = 0;
#pragma unroll
        for (int e = 0; e < SEQ / 256; ++e)
            if (s.su[t * (SEQ / 256) + e] == T) myeq++;
        s.sufA[t] = myeq;
        __syncthreads();
        {
            unsigned int* src = s.sufA;
            unsigned int* dst = s.sufB;
            for (int d = 1; d < 256; d <<= 1) {
                unsigned int v = src[t] + ((t >= d) ? src[t - d] : 0u);
                dst[t] = v;
                __syncthreads();
                unsigned int* tmp = src; src = dst; dst = tmp;
            }
            unsigned int taken = src[t] - myeq;
#pragma unroll
            for (int e = 0; e < SEQ / 256; ++e) {
                int idx = t * (SEQ / 256) + e;
                unsigned int u = s.su[idx];
                if (u > T) s.gsel[idx] = 1;
                else if (u == T) { if (taken < remaining) s.gsel[idx] = 1; taken++; }
            }
        }
        __syncthreads();

        for (int k = t; k < SEQ; k += 256) {
            int valid = (amask[b * SEQ + k] != 0) ? 1 : 0;
            int g = s.gsel[k];
            int r = ((k % RSTRIDE) == 0 && (k / RSTRIDE) < RBUDGET) ? 1 : 0;
            flags[b * SEQ + k] = (unsigned char)(valid | (g << 1) | (r << 2));
        }
        __syncthreads();   // flags drained (vmcnt) + LDS union handoff

        // counts: reads this block's just-written flags (same CU, L1/L2-visible)
        counts_body(flags, out_eff, b, t, sm.cnt);
        return;
    }

    if (bid < X_STATIC_BASE) {
        // ---------------- selected = all True ------------------------------
        int idx = (bid - X_TOPK_BLOCKS) * 256 + t;   // float4 index, 4096 total
        float4 ones = {1.0f, 1.0f, 1.0f, 1.0f};
        ((float4*)out_selected)[idx] = ones;
        return;
    }

    // ---------------- static mask region (no flag dependence) --------------
    int row0 = (bid - X_STATIC_BASE) << 2;   // 4 consecutive global rows
    int b = row0 >> 12;

    const int4* am4 = (const int4*)(amask + b * SEQ);
    unsigned int validBits = 0;
#pragma unroll
    for (int k = 0; k < 4; ++k) {
        int4 m = am4[t + 256 * k];
        validBits |= (unsigned int)(m.x != 0) << (k * 4 + 0);
        validBits |= (unsigned int)(m.y != 0) << (k * 4 + 1);
        validBits |= (unsigned int)(m.z != 0) << (k * 4 + 2);
        validBits |= (unsigned int)(m.w != 0) << (k * 4 + 3);
    }
    int4 mr = *(const int4*)(amask + row0);          // row0 % 4 == 0, same batch
    int vIr[4] = {mr.x != 0, mr.y != 0, mr.z != 0, mr.w != 0};

#pragma unroll
    for (int r = 0; r < 4; ++r) {
        int i = (row0 + r) & (SEQ - 1);
        int vI = vIr[r];
        // first float4-aligned column owned by this kernel
        int c4 = (i <= 127) ? 0 : (((i - 127 + 15) & ~15) >> 2);
        float4* outrow4 = (float4*)(out_sparse + (size_t)(row0 + r) * SEQ);
#pragma unroll
        for (int k = 0; k < 4; ++k) {
            int j4 = t + 256 * k;
            if (j4 < c4) continue;                   // flag-dependent -> kernel Y
            int j0 = j4 << 2;
            float4 v;
#pragma unroll
            for (int e = 0; e < 4; ++e) {
                int j = j0 + e;
                // j >= cut2 >= i-127, so any j<=i is inside the local window
                int one = (j <= i) & vI & (int)((validBits >> (k * 4 + e)) & 1u);
                ((float*)&v)[e] = one ? 1.0f : 0.0f;
            }
            outrow4[j4] = v;                         // plain (temporal) store
        }
    }
}

// ---------------------------------------------------------------------------
// Fused kernel Y: pure writer grid, flag-DEPENDENT region: columns j4 < c4(i).
__global__ void __launch_bounds__(256) fused_dynamic_kernel(
        const unsigned char* __restrict__ flags,
        float* __restrict__ out_sparse) {
    int bid = blockIdx.x, t = threadIdx.x;
    int row0 = bid << 2;
    int b = row0 >> 12;

    const uchar4* f4 = (const uchar4*)(flags + b * SEQ);
    unsigned int validBits = 0, hotBits = 0;
#pragma unroll
    for (int k = 0; k < 4; ++k) {
        uchar4 f = f4[t + 256 * k];
        unsigned char fa[4] = {f.x, f.y, f.z, f.w};
#pragma unroll
        for (int e = 0; e < 4; ++e) {
            int idx = k * 4 + e;
            validBits |= (unsigned int)(fa[e] & 1u) << idx;
            hotBits   |= (unsigned int)((fa[e] & 6u) ? 1u : 0u) << idx;
        }
    }
    uchar4 fr = *(const uchar4*)(flags + row0);
    unsigned char fra[4] = {fr.x, fr.y, fr.z, fr.w};

#pragma unroll
    for (int r = 0; r < 4; ++r) {
        int i = (row0 + r) & (SEQ - 1);
        if (i <= 127) continue;                       // whole row owned by X
        int vI = fra[r] & 1;
        int hotI = (fra[r] & 6) != 0;
        int c4 = ((i - 127 + 15) & ~15) >> 2;         // exclusive upper bound
        float4* outrow4 = (float4*)(out_sparse + (size_t)(row0 + r) * SEQ);
#pragma unroll
        for (int k = 0; k < 4; ++k) {
            int j4 = t + 256 * k;
            if (j4 >= c4) continue;                   // static region -> kernel X
            int j0 = j4 << 2;
            float4 v;
#pragma unroll
            for (int e = 0; e < 4; ++e) {
                int idx = k * 4 + e;
                int j = j0 + e;                       // j < cut2 <= i, so j<=i
                int one = vI & (int)((validBits >> idx) & 1u)
                        & (((i - j) < LOCALW) | hotI | (int)((hotBits >> idx) & 1u));
                ((float*)&v)[e] = one ? 1.0f : 0.0f;
            }
            outrow4[j4] = v;                          // plain (temporal) store
        }
    }
}

extern "C" void kernel_launch(void* const* d_in, const int* in_sizes, int n_in,
                              void* d_out, int out_size, void* d_ws, size_t ws_size,
                              hipStream_t stream) {
    const float* hs    = (const float*)d_in[0];   // [B,S,D] f32
    const int*   amask = (const int*)d_in[1];     // [B,S] i32
    const float* W     = (const float*)d_in[2];   // [1,D] f32

    char* ws = (char*)d_ws;
    float*         scores = (float*)(ws + WS_SCORES_OFF);
    unsigned char* flags  = (unsigned char*)(ws + WS_FLAGS_OFF);

    float* out_sparse   = (float*)d_out;                          // B*S*S
    float* out_selected = out_sparse + (size_t)BATCH * SEQ * SEQ; // B*S
    float* out_eff      = out_selected + BATCH * SEQ;             // B

    // 1) scores: 64 MB read, BW-bound (~10 us)
    scores_kernel<<<TOTAL_ROWS / 4, 256, 0, stream>>>(hs, amask, W, scores);
    // 2) top-k + counts (4 blocks) hidden under the 142 MB static write
    fused_static_kernel<<<X_STATIC_BASE + TOTAL_GROUPS, 256, 0, stream>>>(
        scores, amask, flags, out_sparse, out_selected, out_eff);
    // 3) 126 MB flag-dependent write (uniform writer grid)
    fused_dynamic_kernel<<<TOTAL_GROUPS, 256, 0, stream>>>(flags, out_sparse);
}

// Round 5
// 314.512 us; speedup vs baseline: 1.0495x; 1.0495x over previous
//
#include <hip/hip_runtime.h>
#include <math.h>

// Problem constants (fixed by the reference harness)
#define BATCH 4
#define SEQ   4096
#define DIM   1024
#define TOPK  64          // min(GLOBAL_BUDGET=64, int(4096*0.05)=204)
#define RSTRIDE 10        // max(1, 4096 // 409)
#define RBUDGET 409       // min(4096, int(4096*0.1))
#define LOCALW  128

#define TOTAL_ROWS   (BATCH * SEQ)      // 16384
#define TOTAL_GROUPS (TOTAL_ROWS / 4)   // 4096 groups of 4 rows

typedef float nfloat4 __attribute__((ext_vector_type(4)));  // nontemporal stores

// d_ws layout: scores (B*S floats) then flags (B*S bytes)
#define WS_SCORES_OFF 0
#define WS_FLAGS_OFF  (BATCH * SEQ * sizeof(float))

// Block roles (latency-critical blocks FIRST so they dispatch early):
#define X_TOPK_BLOCKS 4
#define X_SEL_BLOCKS  16
#define X_STATIC_BASE (X_TOPK_BLOCKS + X_SEL_BLOCKS)   // 20
#define Y_CNT_BLOCKS  4

// ---------------------------------------------------------------------------
// One wave (64 lanes) per (b,s) row: score = dot(hidden[b,s,:], W)
__global__ void scores_kernel(const float* __restrict__ hs,
                              const int* __restrict__ amask,
                              const float* __restrict__ W,
                              float* __restrict__ scores) {
    int row  = blockIdx.x * 4 + (threadIdx.x >> 6);   // 4 waves / block
    int lane = threadIdx.x & 63;
    const float4* h4 = (const float4*)(hs + (size_t)row * DIM);
    const float4* w4 = (const float4*)W;
    float acc = 0.0f;
#pragma unroll
    for (int k = 0; k < DIM / 4 / 64; ++k) {          // 4 iterations
        float4 h = h4[lane + 64 * k];
        float4 w = w4[lane + 64 * k];
        acc += h.x * w.x + h.y * w.y + h.z * w.z + h.w * w.w;
    }
#pragma unroll
    for (int off = 32; off; off >>= 1) acc += __shfl_down(acc, off, 64);
    if (lane == 0)
        scores[row] = amask[row] ? acc : -INFINITY;
}

// ---------------------------------------------------------------------------
// Fused kernel X:
//   blocks [0,4)      : exact top-64 per batch (radix select) -> flags
//   blocks [4,20)     : out_selected = 1.0 everywhere (selected is all-True)
//   blocks [20,4116)  : flag-INDEPENDENT mask region: for each row i, columns
//                       j in [cut2(i), SEQ) where cut2 = roundup16(i-127).
//                       There value = (j<=i) & vI & vJ (local band or zero).
__global__ void __launch_bounds__(256) fused_static_kernel(
        const float* __restrict__ scores,
        const int* __restrict__ amask,
        unsigned char* __restrict__ flags,
        float* __restrict__ out_sparse,
        float* __restrict__ out_selected) {
    __shared__ unsigned int su[SEQ];          // orderable keys
    __shared__ unsigned char gsel[SEQ];
    __shared__ unsigned int hist[257];
    __shared__ unsigned int sufA[257];
    __shared__ unsigned int sufB[257];
    __shared__ unsigned int bcast[2];

    int bid = blockIdx.x;
    int t = threadIdx.x;

    if (bid < X_TOPK_BLOCKS) {
        // ---------------- top-k + flag emission (verified radix select) ----
        int b = bid;

        for (int k = t; k < SEQ; k += 256) {
            float s = scores[b * SEQ + k];
            unsigned int x = __float_as_uint(s);
            su[k] = (x & 0x80000000u) ? ~x : (x | 0x80000000u);
            gsel[k] = 0;
        }
        __syncthreads();

        unsigned int prefixVal = 0;
        unsigned int remaining = TOPK;
#pragma unroll
        for (int pass = 0; pass < 4; ++pass) {
            int shift = 24 - 8 * pass;
            unsigned int highmask = (pass == 0) ? 0u : (0xFFFFFFFFu << (shift + 8));

            hist[t] = 0;
            if (t == 0) hist[256] = 0;
            __syncthreads();

#pragma unroll
            for (int e = 0; e < SEQ / 256; ++e) {
                unsigned int u = su[t * (SEQ / 256) + e];
                if ((u & highmask) == prefixVal)
                    atomicAdd(&hist[(u >> shift) & 0xFFu], 1u);
            }
            __syncthreads();

            sufA[t] = hist[t];
            if (t == 0) sufA[256] = 0;
            __syncthreads();
            unsigned int* src = sufA;
            unsigned int* dst = sufB;
            for (int d = 1; d < 256; d <<= 1) {
                unsigned int v = src[t] + ((t + d < 256) ? src[t + d] : 0u);
                dst[t] = v;
                if (t == 0) dst[256] = 0;
                __syncthreads();
                unsigned int* tmp = src; src = dst; dst = tmp;
            }
            if (src[t] >= remaining && src[t + 1] < remaining) {
                bcast[0] = (unsigned int)t;
                bcast[1] = remaining - src[t + 1];
            }
            __syncthreads();
            prefixVal |= (bcast[0] << shift);
            remaining = bcast[1];
            __syncthreads();
        }

        // stable selection of `remaining` lowest-index elements equal to T
        unsigned int T = prefixVal;
        unsigned int myeq = 0;
#pragma unroll
        for (int e = 0; e < SEQ / 256; ++e)
            if (su[t * (SEQ / 256) + e] == T) myeq++;
        sufA[t] = myeq;
        __syncthreads();
        {
            unsigned int* src = sufA;
            unsigned int* dst = sufB;
            for (int d = 1; d < 256; d <<= 1) {
                unsigned int v = src[t] + ((t >= d) ? src[t - d] : 0u);
                dst[t] = v;
                __syncthreads();
                unsigned int* tmp = src; src = dst; dst = tmp;
            }
            unsigned int taken = src[t] - myeq;
#pragma unroll
            for (int e = 0; e < SEQ / 256; ++e) {
                int idx = t * (SEQ / 256) + e;
                unsigned int u = su[idx];
                if (u > T) gsel[idx] = 1;
                else if (u == T) { if (taken < remaining) gsel[idx] = 1; taken++; }
            }
        }
        __syncthreads();

        for (int k = t; k < SEQ; k += 256) {
            int valid = (amask[b * SEQ + k] != 0) ? 1 : 0;
            int g = gsel[k];
            int r = ((k % RSTRIDE) == 0 && (k / RSTRIDE) < RBUDGET) ? 1 : 0;
            flags[b * SEQ + k] = (unsigned char)(valid | (g << 1) | (r << 2));
        }
        return;
    }

    if (bid < X_STATIC_BASE) {
        // ---------------- selected = all True --------------------------------
        int idx = (bid - X_TOPK_BLOCKS) * 256 + t;   // float4 index, 4096 total
        nfloat4 ones = {1.0f, 1.0f, 1.0f, 1.0f};
        __builtin_nontemporal_store(ones, ((nfloat4*)out_selected) + idx);
        return;
    }

    // ---------------- static mask region (no flag dependence) ----------------
    int row0 = (bid - X_STATIC_BASE) << 2;   // 4 consecutive global rows
    int b = row0 >> 12;

    const int4* am4 = (const int4*)(amask + b * SEQ);
    unsigned int validBits = 0;
#pragma unroll
    for (int k = 0; k < 4; ++k) {
        int4 m = am4[t + 256 * k];
        validBits |= (unsigned int)(m.x != 0) << (k * 4 + 0);
        validBits |= (unsigned int)(m.y != 0) << (k * 4 + 1);
        validBits |= (unsigned int)(m.z != 0) << (k * 4 + 2);
        validBits |= (unsigned int)(m.w != 0) << (k * 4 + 3);
    }
    int4 mr = *(const int4*)(amask + row0);          // row0 % 4 == 0, same batch
    int vIr[4] = {mr.x != 0, mr.y != 0, mr.z != 0, mr.w != 0};

#pragma unroll
    for (int r = 0; r < 4; ++r) {
        int i = (row0 + r) & (SEQ - 1);
        int vI = vIr[r];
        // first float4-aligned column owned by this kernel
        int c4 = (i <= 127) ? 0 : (((i - 127 + 15) & ~15) >> 2);
        nfloat4* outrow4 = (nfloat4*)(out_sparse + (size_t)(row0 + r) * SEQ);
#pragma unroll
        for (int k = 0; k < 4; ++k) {
            int j4 = t + 256 * k;
            if (j4 < c4) continue;                   // flag-dependent region -> kernel Y
            int j0 = j4 << 2;
            nfloat4 v;
#pragma unroll
            for (int e = 0; e < 4; ++e) {
                int j = j0 + e;
                // here j >= cut2 >= i-127, so any j<=i is inside the local window
                int one = (j <= i) & vI & (int)((validBits >> (k * 4 + e)) & 1u);
                v[e] = one ? 1.0f : 0.0f;
            }
            __builtin_nontemporal_store(v, outrow4 + j4);
        }
    }
}

// ---------------------------------------------------------------------------
// Fused kernel Y:
//   blocks [0,4)      : analytic connection counts -> out_eff (bit-packed
//                       prefix sums, small LDS)
//   blocks [4,4100)   : flag-DEPENDENT mask region: columns j in [0, cut2(i)).
//                       Block order REVERSED so heavy rows (high i) go first.
__global__ void __launch_bounds__(256) fused_dynamic_kernel(
        const unsigned char* __restrict__ flags,
        float* __restrict__ out_sparse,
        float* __restrict__ out_eff) {
    __shared__ unsigned int vb[256], hb[256];
    __shared__ int tA[256], tB[256], tC[256], tD[256];
    __shared__ int exV[256], exH[256];
    __shared__ int red[256];

    int bid = blockIdx.x, t = threadIdx.x;

    if (bid < Y_CNT_BLOCKS) {
        // ---------------- connection count ----------------------------------
        int b = bid, base = b * SEQ;
        const unsigned char* fp = flags + base + t * 16;
        unsigned int myv = 0, myh = 0;
#pragma unroll
        for (int e = 0; e < 16; ++e) {
            unsigned char f = fp[e];
            unsigned int v = f & 1u;
            unsigned int h = v & ((f & 6u) ? 1u : 0u);
            myv |= v << e;
            myh |= h << e;
        }
        vb[t] = myv; hb[t] = myh;
        int sv = __popc(myv), sh = __popc(myh);
        tA[t] = sv; tC[t] = sh;
        __syncthreads();
        int* vsrc = tA; int* vdst = tB;
        int* hsrc = tC; int* hdst = tD;
        for (int d = 1; d < 256; d <<= 1) {
            int av = vsrc[t] + ((t >= d) ? vsrc[t - d] : 0);
            int ah = hsrc[t] + ((t >= d) ? hsrc[t - d] : 0);
            vdst[t] = av; hdst[t] = ah;
            __syncthreads();
            int* tmp = vsrc; vsrc = vdst; vdst = tmp;
            tmp = hsrc; hsrc = hdst; hdst = tmp;
        }
        exV[t] = vsrc[t] - sv;
        exH[t] = hsrc[t] - sh;
        __syncthreads();

        int exVt = exV[t];
        int exV8 = (t >= 8) ? exV[t - 8] : 0;
        int exH8 = (t >= 8) ? exH[t - 8] : 0;
        unsigned int vb8 = (t >= 8) ? vb[t - 8] : 0u;
        unsigned int hb8 = (t >= 8) ? hb[t - 8] : 0u;
        int cnt = 0;
#pragma unroll
        for (int e = 0; e < 16; ++e) {
            unsigned int m = (2u << e) - 1u;         // bits 0..e
            int validI = (int)((myv >> e) & 1u);
            int hotI   = (int)((myh >> e) & 1u);
            int cumVi = exVt + __popc(myv & m);      // cumV[i], i = t*16+e
            int c;
            if (t >= 8) {                            // i >= 128
                int cumVm = exV8 + __popc(vb8 & m);  // cumV[i-128]
                int cumHm = exH8 + __popc(hb8 & m);  // cumH[i-128]
                c = hotI ? cumVi : (cumVi - cumVm + cumHm);
            } else {
                c = cumVi;                           // i<128: window covers all
            }
            cnt += validI ? c : 0;
        }
        red[t] = cnt;
        __syncthreads();
        for (int s2 = 128; s2; s2 >>= 1) {
            if (t < s2) red[t] += red[t + s2];
            __syncthreads();
        }
        if (t == 0)
            out_eff[b] = (float)red[0] * (1.0f / ((float)SEQ * (float)SEQ));
        return;
    }

    // ---------------- dynamic mask region (needs flags) ----------------------
    // Reverse map: heavy groups (high i within each batch) dispatch first.
    int g = TOTAL_GROUPS - 1 - (bid - Y_CNT_BLOCKS);
    int row0 = g << 2;
    int b = row0 >> 12;

    const uchar4* f4 = (const uchar4*)(flags + b * SEQ);
    unsigned int validBits = 0, hotBits = 0;
#pragma unroll
    for (int k = 0; k < 4; ++k) {
        uchar4 f = f4[t + 256 * k];
        unsigned char fa[4] = {f.x, f.y, f.z, f.w};
#pragma unroll
        for (int e = 0; e < 4; ++e) {
            int idx = k * 4 + e;
            validBits |= (unsigned int)(fa[e] & 1u) << idx;
            hotBits   |= (unsigned int)((fa[e] & 6u) ? 1u : 0u) << idx;
        }
    }
    uchar4 fr = *(const uchar4*)(flags + row0);
    unsigned char fra[4] = {fr.x, fr.y, fr.z, fr.w};

#pragma unroll
    for (int r = 0; r < 4; ++r) {
        int i = (row0 + r) & (SEQ - 1);
        if (i <= 127) continue;                       // whole row owned by X
        int vI = fra[r] & 1;
        int hotI = (fra[r] & 6) != 0;
        int c4 = ((i - 127 + 15) & ~15) >> 2;         // exclusive upper bound
        nfloat4* outrow4 = (nfloat4*)(out_sparse + (size_t)(row0 + r) * SEQ);
#pragma unroll
        for (int k = 0; k < 4; ++k) {
            int j4 = t + 256 * k;
            if (j4 >= c4) continue;                   // static region -> kernel X
            int j0 = j4 << 2;
            nfloat4 v;
#pragma unroll
            for (int e = 0; e < 4; ++e) {
                int idx = k * 4 + e;
                int j = j0 + e;                       // j < cut2 <= i, so j<=i holds
                int one = vI & (int)((validBits >> idx) & 1u)
                        & (((i - j) < LOCALW) | hotI | (int)((hotBits >> idx) & 1u));
                v[e] = one ? 1.0f : 0.0f;
            }
            __builtin_nontemporal_store(v, outrow4 + j4);
        }
    }
}

extern "C" void kernel_launch(void* const* d_in, const int* in_sizes, int n_in,
                              void* d_out, int out_size, void* d_ws, size_t ws_size,
                              hipStream_t stream) {
    const float* hs    = (const float*)d_in[0];   // [B,S,D] f32
    const int*   amask = (const int*)d_in[1];     // [B,S] i32
    const float* W     = (const float*)d_in[2];   // [1,D] f32

    char* ws = (char*)d_ws;
    float*         scores = (float*)(ws + WS_SCORES_OFF);
    unsigned char* flags  = (unsigned char*)(ws + WS_FLAGS_OFF);

    float* out_sparse   = (float*)d_out;                          // B*S*S
    float* out_selected = out_sparse + (size_t)BATCH * SEQ * SEQ; // B*S
    float* out_eff      = out_selected + BATCH * SEQ;             // B

    // 1) scores: 64 MB read, BW-bound (~10 us)
    scores_kernel<<<TOTAL_ROWS / 4, 256, 0, stream>>>(hs, amask, W, scores);
    // 2) top-k (4 blocks) hidden under the 142 MB flag-independent write
    fused_static_kernel<<<X_STATIC_BASE + TOTAL_GROUPS, 256, 0, stream>>>(
        scores, amask, flags, out_sparse, out_selected);
    // 3) counts (4 blocks) hidden under the 126 MB flag-dependent write
    fused_dynamic_kernel<<<Y_CNT_BLOCKS + TOTAL_GROUPS, 256, 0, stream>>>(
        flags, out_sparse, out_eff);
}